// Round 8
// baseline (67.871 us; speedup 1.0000x reference)
//
#include <hip/hip_runtime.h>
#include <math.h>

// Bit-exact float32 replication of the JAX-CPU reference chain.
#pragma clang fp contract(off)

#define BN 65536
#define SN 4
#define HH 128
#define WW 128

// ---------- bit-exact prologue math (validated R1-R7) ----------
__device__ __forceinline__ void inv4(const float* P, float U[4][4]) {
#pragma clang fp contract(off)
    float a = P[10];
    float b = P[11];
    float ra = 1.0f / a;
    float l32 = P[14] * ra;
    float t = l32 * b;
    float u33 = 0.0f - t;
    float rf0 = 1.0f / P[0];
    float rf1 = 1.0f / P[5];
    float ru  = 1.0f / u33;
#pragma unroll
    for (int i = 0; i < 4; i++)
#pragma unroll
        for (int j = 0; j < 4; j++) U[i][j] = 0.0f;
    U[0][0] = rf0;
    U[1][1] = rf1;
    float x3c2 = (0.0f - l32) * ru;
    float y2c2 = fmaf(0.0f - b, x3c2, 1.0f);
    U[2][2] = y2c2 * ra;
    U[3][2] = x3c2;
    float x3c3 = ru;
    float y2c3 = 0.0f - (b * x3c3);
    U[2][3] = y2c3 * ra;
    U[3][3] = x3c3;
}

__device__ __forceinline__ void xform(const float M[4][4], float x, float y, float z,
                                      float& ox, float& oy, float& oz) {
#pragma clang fp contract(off)
    float o[4];
#pragma unroll
    for (int i = 0; i < 4; i++) {
        float acc = x * M[i][0];
        acc = acc + y * M[i][1];
        acc = acc + z * M[i][2];
        acc = acc + M[i][3];
        o[i] = acc;
    }
    ox = o[0] / o[3];
    oy = o[1] / o[3];
    oz = o[2] / o[3];
}

struct RS {
    float p0, p1, p2, d0, d1, d2;
    float y0, y1;          // RN(1/d0), RN(1/d1) — IEEE div, once per ray
    float fx, cy1;         // exact (cx+sx)/128 and 1-(cy+sy)/128
    float sxf, syf;        // sx/128, sy/128 (exact)
    float da, db, dc, hdz;
    int cx, cy, sx, sy, base, B, hoff, hk;
    bool still, testing, hit;
};

__device__ __forceinline__ void make_ray(RS& S, int r, const float* proj,
                                         const int* idxA, const int* xA, const int* yA,
                                         const float* dA, const float* dsA) {
#pragma clang fp contract(off)
    float P[4][4];
#pragma unroll
    for (int i = 0; i < 16; i++) ((float*)P)[i] = proj[i];
    float U[4][4];
    inv4(proj, U);
    int xi = xA[r], yi = yA[r];
    float t0 = ((float)xi + 0.5f) / 128.0f;
    float t1 = 1.0f - ((float)yi + 0.5f) / 128.0f;
    float ux = t0 * 2.0f - 1.0f;
    float uy = t1 * 2.0f - 1.0f;
    float ds = dsA[r] * 2.0f - 1.0f;
    float vx, vy, vz;
    xform(U, ux, uy, ds, vx, vy, vz);
    float ex = vx + dA[3 * r + 0] * 0.001f;
    float ey = vy + dA[3 * r + 1] * 0.001f;
    float ez = vz + dA[3 * r + 2] * 0.001f;
    float qx, qy, qz;
    xform(P, ex, ey, ez, qx, qy, qz);
    S.d0 = qx - ux;
    S.d1 = qy - uy;
    S.d2 = qz - ds;
    S.p0 = (ux + 1.0f) * 0.5f;
    S.p1 = (uy + 1.0f) * 0.5f;
    S.p2 = (ds + 1.0f) * 0.5f;
    S.sx = (S.d0 >= 0.0f) ? 1 : -1;
    S.sy = (S.d1 >= 0.0f) ? -1 : 1;
    S.cx = xi;
    S.cy = yi;
    // --- initial march (bit-identical to reference _march_next) ---
    {
        float nbx = (float)(S.cx + S.sx) / 128.0f;
        float nby = (float)(S.cy + S.sy) / 128.0f;
        float c1 = 1.0f - nby;
        float s0 = (nbx - S.p0) / S.d0;     // IEEE div (prologue only)
        float s1 = (c1 - S.p1) / S.d1;
        bool ty = s0 > s1;
        float t = ty ? s1 : s0;
        if (s1 != s1) t = s1;
        S.p0 = S.p0 + S.d0 * t;
        S.p1 = S.p1 + S.d1 * t;
        S.p2 = S.p2 + S.d2 * t;
        if (ty) S.cy += S.sy; else S.cx += S.sx;
    }
    S.y0 = 1.0f / S.d0;
    S.y1 = 1.0f / S.d1;
    S.fx  = (float)(S.cx + S.sx) / 128.0f;           // exact multiple of 1/128
    S.cy1 = 1.0f - (float)(S.cy + S.sy) / 128.0f;    // exact
    S.sxf = (float)S.sx * 0.0078125f;
    S.syf = (float)S.sy * 0.0078125f;
    S.da = dA[3 * r + 0]; S.db = dA[3 * r + 1]; S.dc = dA[3 * r + 2];
    S.base = idxA[r] * (HH * WW);
    S.B = 0; S.hoff = 0; S.hk = 0; S.hdz = 0.0f;
    S.still = true; S.testing = true; S.hit = false;
}

__global__ void k_zero(int* ws) { ws[0] = 0; }

// Packed per-cell float4 table: (z, n0, n1, n2). 1 MB, L2-resident.
__global__ __launch_bounds__(256) void k_pack(const float* __restrict__ depth,
                                              const float* __restrict__ normal,
                                              float4* __restrict__ tab) {
    int t = blockIdx.x * 256 + threadIdx.x;
    int s = t >> 14;
    int c = t & 16383;
    float4 v;
    v.x = depth[t];
    v.y = normal[s * 3 * HH * WW + c];
    v.z = normal[s * 3 * HH * WW + HH * WW + c];
    v.w = normal[s * 3 * HH * WW + 2 * HH * WW + c];
    tab[t] = v;
}

// Phase A: exec-gated gathers (retired lanes cost ZERO TA address slots) with
// block-deferred consumes on a 2-bank × 8-slot pipeline: a whole block of
// loads is issued (8 states of march between issue and consume), so even a
// conservative vmcnt(0) at the consume point has ~700cy of cover.
// Phase B: lean march-only loop finishing the in-box prefix accounting.
template <bool PACKED>
__global__ __launch_bounds__(256) void k_march8(const float* __restrict__ depth,
                                                const float* __restrict__ normal,
                                                const float4* __restrict__ tab,
                                                const int* idxA, const float* proj,
                                                const int* xA, const int* yA,
                                                const float* dA, const float* dsA,
                                                float* out, int* ws) {
#pragma clang fp contract(off)
    int r = blockIdx.x * 256 + threadIdx.x;
    RS S;
    make_ray(S, r, proj, idxA, xA, yA, dA, dsA);
    const float* dep = depth + S.base;
    const float* nrm = normal + 3 * S.base;

#define DECLS(bk, u) \
    float z##bk##u = 0.0f, a##bk##u = 0.0f, b##bk##u = 0.0f, c##bk##u = 0.0f, \
          q##bk##u = 0.0f; \
    int o##bk##u = 0; bool v##bk##u = false;
    DECLS(A,0) DECLS(A,1) DECLS(A,2) DECLS(A,3)
    DECLS(A,4) DECLS(A,5) DECLS(A,6) DECLS(A,7)
    DECLS(B,0) DECLS(B,1) DECLS(B,2) DECLS(B,3)
    DECLS(B,4) DECLS(B,5) DECLS(B,6) DECLS(B,7)
#undef DECLS

#define CONSUME(bk, u, kcons) { \
        float t0 = S.da * a##bk##u; \
        float t1 = S.db * b##bk##u; \
        float t2 = S.dc * c##bk##u; \
        float dotv = (t0 + t1) + t2; \
        bool hc = v##bk##u && (q##bk##u >= z##bk##u) && (dotv <= 0.0f) && !S.hit; \
        S.hit = S.hit || hc; \
        S.hoff = hc ? o##bk##u : S.hoff; \
        S.hk   = hc ? (kcons) : S.hk; \
        float dzn = q##bk##u - z##bk##u; \
        S.hdz  = hc ? dzn : S.hdz; \
        v##bk##u = false; }

#define BOXCHK(inow) { \
        bool ib = (S.p0 >= 0.0f) && (S.p0 <= 1.0f) && \
                  (S.p1 >= 0.0f) && (S.p1 <= 1.0f) && \
                  (S.p2 > 0.0f) && (S.p2 < 1.0f); \
        S.still = S.still && ib; \
        S.B = S.still ? ((inow) + 1) : S.B; }

#define MARCH { /* Markstein correctly-rounded div-by-invariant (validated) */ \
        float x0 = S.fx - S.p0; \
        float x1 = S.cy1 - S.p1; \
        float q0a = x0 * S.y0; \
        float rra = fmaf(-S.d0, q0a, x0); \
        float s0v = fmaf(rra, S.y0, q0a); \
        float q0b = x1 * S.y1; \
        float rrb = fmaf(-S.d1, q0b, x1); \
        float s1v = fmaf(rrb, S.y1, q0b); \
        bool ty = s0v > s1v; \
        float t = ty ? s1v : s0v; \
        t = (s1v != s1v) ? s1v : t; \
        float m0 = S.d0 * t; S.p0 = S.p0 + m0; \
        float m1 = S.d1 * t; S.p1 = S.p1 + m1; \
        float m2 = S.d2 * t; S.p2 = S.p2 + m2; \
        S.cx  += ty ? 0 : S.sx; \
        S.cy  += ty ? S.sy : 0; \
        S.fx  += ty ? 0.0f : S.sxf; \
        S.cy1 -= ty ? S.syf : 0.0f; }

// Issue one state: box-account, exec-gated gather into slot (bk,u), march.
#define ISSUE1(bk, u, inow) { \
        BOXCHK(inow) \
        { bool inpix = ((unsigned)S.cx < (unsigned)WW) && ((unsigned)S.cy < (unsigned)HH); \
          S.testing = S.testing && inpix && !S.hit; \
          int off = S.cy * WW + S.cx; \
          v##bk##u = S.testing; o##bk##u = off; q##bk##u = S.p2; \
          if (S.testing) {                 /* exec-skip: zero TA for idle lanes */ \
              if (PACKED) { \
                  float4 vv = tab[S.base + off]; \
                  z##bk##u = vv.x; a##bk##u = vv.y; b##bk##u = vv.z; c##bk##u = vv.w; \
              } else { \
                  z##bk##u = dep[off]; \
                  a##bk##u = nrm[off]; \
                  b##bk##u = nrm[HH * WW + off]; \
                  c##bk##u = nrm[2 * HH * WW + off]; \
              } \
          } } \
        MARCH }

#define ISSUE_BLOCK(bk, base) \
        ISSUE1(bk,0,(base))   ISSUE1(bk,1,(base)+1) ISSUE1(bk,2,(base)+2) \
        ISSUE1(bk,3,(base)+3) ISSUE1(bk,4,(base)+4) ISSUE1(bk,5,(base)+5) \
        ISSUE1(bk,6,(base)+6) ISSUE1(bk,7,(base)+7)

#define CONSUME_BLOCK(bk, base) \
        CONSUME(bk,0,(base))   CONSUME(bk,1,(base)+1) CONSUME(bk,2,(base)+2) \
        CONSUME(bk,3,(base)+3) CONSUME(bk,4,(base)+4) CONSUME(bk,5,(base)+5) \
        CONSUME(bk,6,(base)+6) CONSUME(bk,7,(base)+7)

    int i = 0;
    // ---- Phase A: software-pipelined at block granularity ----
    ISSUE_BLOCK(A, 0)
    i = 8;
    while (true) {
        ISSUE_BLOCK(B, i)            // states i..i+7 (loads have 8-state cover)
        CONSUME_BLOCK(A, i - 8)      // states i-8..i-1 (first-hit state order)
        if (!__any(S.testing) || i >= 4080) {
            CONSUME_BLOCK(B, i)
            i += 8;
            break;
        }
        i += 8;
        ISSUE_BLOCK(A, i)
        CONSUME_BLOCK(B, i - 8)
        if (!__any(S.testing) || i >= 4080) {
            CONSUME_BLOCK(A, i)
            i += 8;
            break;
        }
        i += 8;
    }

    // ---- Phase B: march-only, finish in-box prefix accounting ----
    while (i < 4096 && __any(S.still)) {
#pragma unroll
        for (int u = 0; u < 8; ++u) {
            BOXCHK(i + u)
            MARCH
        }
        i += 8;
    }
#undef ISSUE_BLOCK
#undef CONSUME_BLOCK
#undef ISSUE1
#undef MARCH
#undef BOXCHK
#undef CONSUME

    // record (hoff == (ry<<7)|rx since hits are always in-pixel)
    int pk = S.hit ? (S.hoff | (1 << 14)) : 0;
    out[2 * r]      = (float)pk;
    out[2 * r + 1]  = (float)S.hk;
    out[3 * BN + r] = S.hdz;

    // N = max over all rays of in-box prefix length
    int Bm = S.B;
    for (int o = 32; o; o >>= 1) {
        int v = __shfl_down(Bm, o, 64);
        Bm = Bm > v ? Bm : v;
    }
    if ((threadIdx.x & 63) == 0) atomicMax(ws, Bm);
}

// Finalize: hit valid iff first-hit state index k < N (global trip count).
__global__ __launch_bounds__(256) void k_final(float* out, const int* ws) {
    int r = blockIdx.x * 256 + threadIdx.x;
    int N = ws[0];
    int pk = (int)out[2 * r];
    int k  = (int)out[2 * r + 1];
    float dzv = out[3 * BN + r];
    bool hit = (pk >> 14) & 1;
    bool ok = hit && (k < N);
    int rx = pk & 127, ry = (pk >> 7) & 127;
    out[2 * r]      = ok ? (float)rx : 0.0f;
    out[2 * r + 1]  = ok ? (float)ry : 0.0f;
    out[2 * BN + r] = ok ? 1.0f : 0.0f;
    out[3 * BN + r] = ok ? dzv : 0.0f;
}

extern "C" void kernel_launch(void* const* d_in, const int* in_sizes, int n_in,
                              void* d_out, int out_size, void* d_ws, size_t ws_size,
                              hipStream_t stream) {
    const float* depth = (const float*)d_in[0];
    const float* normal = (const float*)d_in[1];
    const int* indices = (const int*)d_in[2];
    const float* proj = (const float*)d_in[3];
    const int* x = (const int*)d_in[4];
    const int* y = (const int*)d_in[5];
    const float* d = (const float*)d_in[6];
    const float* ds = (const float*)d_in[7];
    float* out = (float*)d_out;
    int* ws = (int*)d_ws;

    const size_t tab_off = 64;
    const size_t need = tab_off + (size_t)SN * HH * WW * 16;
    float4* tab = (float4*)((char*)d_ws + tab_off);

    k_zero<<<1, 1, 0, stream>>>(ws);
    if (ws_size >= need) {   // host-uniform: graph-capture safe
        k_pack<<<(SN * HH * WW) / 256, 256, 0, stream>>>(depth, normal, tab);
        k_march8<true><<<BN / 256, 256, 0, stream>>>(depth, normal, tab, indices,
                                                     proj, x, y, d, ds, out, ws);
    } else {
        k_march8<false><<<BN / 256, 256, 0, stream>>>(depth, normal, tab, indices,
                                                      proj, x, y, d, ds, out, ws);
    }
    k_final<<<BN / 256, 256, 0, stream>>>(out, ws);
}